// Round 12
// baseline (143.962 us; speedup 1.0000x reference)
//
#include <hip/hip_runtime.h>
#include <math.h>

#define Bn  16
#define Tn  8192
#define Dn  128
#define Cn  64
#define Gn  8     // chunks per group
#define NGn 16    // groups per batch
#define GCn 512   // rows per group

typedef __attribute__((ext_vector_type(8)))  short short8v;
typedef __attribute__((ext_vector_type(16))) float f32x16;

#define AK  200   // A_cat stride (bf16), 64 rows: [attn(0..63) | Q2(64..191)]
#define BK  200   // B_cat stride (bf16), 128 rows: [d][ V^T(c, swz) | S^T(64+e) ]
#define KDs 136   // Kd stride (bf16), 64 rows  (lam^{-(j+1)} * k, row-major)
#define KTs 72    // KwT stride (bf16), 128 rows ([e][c] = lam^{63-c} * k[c][e], swz)
#define KFs 132   // kf stride (f32), 64 rows (k, then in-place prefix-decayed kappa)
#define K1s 72    // k1 kT/vT stride (bf16)

#define SWZ(row) ((((row) >> 2) & 7) << 3)

// raw barrier: LDS visibility only, does NOT drain vmcnt (keeps prefetch in flight)
#define BAR() do { asm volatile("s_waitcnt lgkmcnt(0)" ::: "memory"); \
                   __builtin_amdgcn_s_barrier(); \
                   asm volatile("" ::: "memory"); } while (0)

__device__ __forceinline__ float sig_(float x){ return 1.0f/(1.0f+expf(-x)); }

__device__ __forceinline__ unsigned short f2bf(float f){
    __bf16 h = (__bf16)f;
    return __builtin_bit_cast(unsigned short, h);
}
__device__ __forceinline__ void st4(unsigned short* p, float a, float b, float c, float d){
    ushort4 u; u.x = f2bf(a); u.y = f2bf(b); u.z = f2bf(c); u.w = f2bf(d);
    *(ushort4*)p = u;   // ds_write_b64
}

// VALU-pipe cross-lane add (DPP); CTRL is an immediate via template param
template<int CTRL>
__device__ __forceinline__ float dppadd(float x){
    int y = __builtin_amdgcn_update_dpp(0, __builtin_bit_cast(int, x), CTRL, 0xf, 0xf, true);
    return x + __builtin_bit_cast(float, y);
}
// reduce over each 32-lane half: quad xor1, xor2, row ror4, ror8, bcast15
// result valid in lanes 16..31 (sum of lanes 0..31) and 48..63 (sum of 32..63)
__device__ __forceinline__ float red32(float x){
    x = dppadd<0xB1>(x);    // quad_perm [1,0,3,2]
    x = dppadd<0x4E>(x);    // quad_perm [2,3,0,1]
    x = dppadd<0x124>(x);   // row_ror:4
    x = dppadd<0x128>(x);   // row_ror:8
    x = dppadd<0x142>(x);   // row_bcast:15
    return x;
}

// -------------------------------------------------------------------------
// K1 (MFMA): A_g = (Kw)^T @ V ; ksum_g f32 register partials.  (HBM-floor)
// -------------------------------------------------------------------------
__global__ __launch_bounds__(512)
void k1_mfma(const float* __restrict__ kin, const float* __restrict__ vin,
             const float* __restrict__ log_decay,
             float* __restrict__ A, float* __restrict__ ksumg)
{
    const int g = blockIdx.x, b = blockIdx.y;
    const int tid  = threadIdx.x;
    const int wid  = tid >> 6;
    const int lane = tid & 63;
    const int l31  = lane & 31;
    const int lhi  = lane >> 5;
    const float lam = sig_(log_decay[0]);

    __shared__ __align__(16) unsigned short kT[128*K1s];
    __shared__ __align__(16) unsigned short vT[128*K1s];
    __shared__ float wt[GCn];
    __shared__ __align__(16) float ps[16*132];

    wt[tid] = powf(lam, (float)(GCn-1 - tid));

    const size_t base = ((size_t)b*Tn + (size_t)g*GCn)*Dn;
    const int rb = tid >> 5;
    const int cb = (tid & 31)*4;

    f32x16 acc[2];
    #pragma unroll
    for (int p = 0; p < 2; ++p)
        #pragma unroll
        for (int r = 0; r < 16; ++r) acc[p][r] = 0.f;
    float ksp[4] = {0.f, 0.f, 0.f, 0.f};

    float kv[4][4], vv[4][4];
    {
        const float* kp = kin + base;
        const float* vp = vin + base;
        #pragma unroll
        for (int u = 0; u < 4; ++u) {
            float4 t4 = *(const float4*)&kp[(size_t)(rb*4+u)*Dn + cb];
            kv[u][0]=t4.x; kv[u][1]=t4.y; kv[u][2]=t4.z; kv[u][3]=t4.w;
            float4 s4 = *(const float4*)&vp[(size_t)(rb*4+u)*Dn + cb];
            vv[u][0]=s4.x; vv[u][1]=s4.y; vv[u][2]=s4.z; vv[u][3]=s4.w;
        }
    }
    BAR();

    const int tr0 = (wid >> 2)*2;
    const int tc  = (wid & 3)*32;

    for (int t = 0; t < 8; ++t) {
        const int r0 = rb*4;
        float w0 = wt[t*64 + r0+0], w1 = wt[t*64 + r0+1];
        float w2 = wt[t*64 + r0+2], w3 = wt[t*64 + r0+3];
        #pragma unroll
        for (int e = 0; e < 4; ++e) {
            int row = cb+e, col = r0 ^ SWZ(row);
            float a0 = kv[0][e]*w0, a1 = kv[1][e]*w1, a2 = kv[2][e]*w2, a3 = kv[3][e]*w3;
            ksp[e] += (a0 + a1) + (a2 + a3);
            st4(&kT[row*K1s + col], a0, a1, a2, a3);
            st4(&vT[row*K1s + col], vv[0][e], vv[1][e], vv[2][e], vv[3][e]);
        }
        BAR();

        if (t < 7) {
            const float* kp = kin + base + (size_t)(t+1)*64*Dn;
            const float* vp = vin + base + (size_t)(t+1)*64*Dn;
            #pragma unroll
            for (int u = 0; u < 4; ++u) {
                float4 t4 = *(const float4*)&kp[(size_t)(rb*4+u)*Dn + cb];
                kv[u][0]=t4.x; kv[u][1]=t4.y; kv[u][2]=t4.z; kv[u][3]=t4.w;
                float4 s4 = *(const float4*)&vp[(size_t)(rb*4+u)*Dn + cb];
                vv[u][0]=s4.x; vv[u][1]=s4.y; vv[u][2]=s4.z; vv[u][3]=s4.w;
            }
        }

        #pragma unroll
        for (int kk = 0; kk < 4; ++kk) {
            int rB = tc + l31;
            short8v bf = *(const short8v*)&vT[rB*K1s + ((kk*16 + lhi*8) ^ SWZ(rB))];
            #pragma unroll
            for (int p = 0; p < 2; ++p) {
                int rA = (tr0+p)*32 + l31;
                short8v af = *(const short8v*)&kT[rA*K1s + ((kk*16 + lhi*8) ^ SWZ(rA))];
                acc[p] = __builtin_amdgcn_mfma_f32_32x32x16_bf16(af, bf, acc[p], 0, 0, 0);
            }
        }
        BAR();
    }

    float* Ab = A + ((size_t)(b*NGn + g))*Dn*Dn;
    #pragma unroll
    for (int p = 0; p < 2; ++p) {
        #pragma unroll
        for (int r = 0; r < 16; ++r) {
            int i = (tr0+p)*32 + (r&3) + 8*(r>>2) + 4*lhi;
            Ab[(size_t)i*Dn + tc + l31] = acc[p][r];
        }
    }

    *(float4*)&ps[rb*132 + cb] = make_float4(ksp[0], ksp[1], ksp[2], ksp[3]);
    BAR();
    if (tid < Dn) {
        float s = 0.f;
        #pragma unroll
        for (int q = 0; q < 16; ++q) s += ps[q*132 + tid];
        ksumg[((size_t)(b*NGn+g))*Dn + tid] = s;
    }
}

// -------------------------------------------------------------------------
// K2: exclusive scan over groups; final carry -> d_out state/z sections.
// -------------------------------------------------------------------------
__global__ __launch_bounds__(256)
void k2_scan(const float* __restrict__ A, const float* __restrict__ ksumg,
             const float* __restrict__ log_decay,
             float* __restrict__ Sg, float* __restrict__ zg,
             float* __restrict__ outState, float* __restrict__ outZ)
{
    const int idx = blockIdx.x*256 + threadIdx.x;
    const float lam = sig_(log_decay[0]);
    const float dG = powf(lam, (float)GCn);
    const int NSTATE = Bn*Dn*Dn;
    if (idx < NSTATE) {
        const int b = idx >> 14, ij = idx & 16383;
        float s = 0.f;
        #pragma unroll
        for (int g = 0; g < NGn; ++g) {
            size_t o = (((size_t)(b*NGn+g)) << 14) + ij;
            Sg[o] = s;
            s = dG*s + A[o];
        }
        outState[idx] = s;
    } else if (idx < NSTATE + Bn*Dn) {
        const int j = idx - NSTATE, b = j >> 7, d = j & 127;
        float s = 0.f;
        #pragma unroll
        for (int g = 0; g < NGn; ++g) {
            size_t o = (size_t)(b*NGn+g)*Dn + d;
            zg[o] = s;
            s = dG*s + ksumg[o];
        }
        outZ[j] = s;
    }
}

// -------------------------------------------------------------------------
// K3: round-9 schedule + (512,1) VGPR headroom + DPP stepB + 16-frag preload.
//  P0: stage(m) from regs; prefetch(m+1); b1
//  P1: w0-1 kappa | w2-3 attn | w4-7 state MFMA; ALL: preload paf[8]+pbf[8]; b2
//  P2: read afa[4]+bfv[4]; stepB (qc regs + kf + zf, DPP reduce);
//      8 reg-only MFMAs then 4 LDS-fed MFMAs; b3
//  P3: epilogue stores; S^T writeback; z update; b4
// -------------------------------------------------------------------------
__global__ __launch_bounds__(512, 1)
void k3_mfma(const float* __restrict__ qin, const float* __restrict__ kin,
             const float* __restrict__ vin, const float* __restrict__ log_decay,
             const float* __restrict__ Sg, const float* __restrict__ zg,
             float* __restrict__ out)
{
    const int g = blockIdx.x, b = blockIdx.y;
    const int tid  = threadIdx.x;
    const int wid  = tid >> 6;
    const int lane = tid & 63;
    const int l31  = lane & 31;
    const int lhi  = lane >> 5;
    const float lam   = sig_(log_decay[0]);
    const float lam64 = powf(lam, 64.0f);

    __shared__ __align__(16) unsigned short sA [64*AK];
    __shared__ __align__(16) unsigned short sB [128*BK];
    __shared__ __align__(16) unsigned short sKd[64*KDs];
    __shared__ __align__(16) unsigned short sKT[128*KTs];
    __shared__ __align__(16) float kf[64*KFs];
    __shared__ __align__(16) float zf[128];
    __shared__ __align__(16) float izb[64], czb[64];
    __shared__ float ptabs[66], ntabs[64];

    const int bg = b*NGn + g;
    const size_t base = (size_t)b*Tn + (size_t)g*Gn*Cn;

    // ---- init ----
    if (tid < 66)  ptabs[tid] = powf(lam, (float)tid);
    if (tid >= 66 && tid < 130) ntabs[tid-66] = powf(lam, -(float)(tid-65));
    if (tid < 128) zf[tid] = zg[(size_t)bg*Dn + tid];

    f32x16 sacc[4];
    if (wid >= 4) {
        const float* Sgp = Sg + ((size_t)bg << 14);
        const int er0 = (wid-4)*32;
        #pragma unroll
        for (int ct = 0; ct < 4; ++ct) {
            const int d = ct*32 + l31;
            #pragma unroll
            for (int r = 0; r < 16; ++r) {
                int e = er0 + (r&3) + 8*(r>>2) + 4*lhi;
                sacc[ct][r] = Sgp[e*Dn + d];
            }
            #pragma unroll
            for (int q = 0; q < 4; ++q) {
                int e0 = er0 + 8*q + 4*lhi;
                st4(&sB[d*BK + 64 + e0],
                    sacc[ct][4*q], sacc[ct][4*q+1], sacc[ct][4*q+2], sacc[ct][4*q+3]);
            }
        }
    }

    // unified staging map: rows a4..a4+3, cols b4c..b4c+3 (q, k, v)
    const int a4  = (tid >> 5)*4;
    const int b4c = (tid & 31)*4;

    // ---- prologue: prefetch chunk 0 ----
    float qv[4][4], kv[4][4], vv[4][4];
    #pragma unroll
    for (int u = 0; u < 4; ++u) {
        float4 tq = *(const float4*)&qin[(base + a4+u)*Dn + b4c];
        qv[u][0]=tq.x; qv[u][1]=tq.y; qv[u][2]=tq.z; qv[u][3]=tq.w;
        float4 tk = *(const float4*)&kin[(base + a4+u)*Dn + b4c];
        kv[u][0]=tk.x; kv[u][1]=tk.y; kv[u][2]=tk.z; kv[u][3]=tk.w;
        float4 tv = *(const float4*)&vin[(base + a4+u)*Dn + b4c];
        vv[u][0]=tv.x; vv[u][1]=tv.y; vv[u][2]=tv.z; vv[u][3]=tv.w;
    }

    const int r0 = (wid >> 2)*32;
    const int c0 = (wid & 3)*32;

    BAR();   // init visible

    for (int m = 0; m < Gn; ++m) {
        const size_t rowbase = base + (size_t)m*Cn;

        // ================= P0: stage chunk m from regs =================
        float qc[4][4];   // q kept live to P2 (stepB)
        #pragma unroll
        for (int u = 0; u < 4; ++u) {
            const int row = a4 + u;
            const float s = ptabs[row+1];
            st4(&sA[row*AK + 64 + b4c], qv[u][0]*s, qv[u][1]*s, qv[u][2]*s, qv[u][3]*s);
            #pragma unroll
            for (int x = 0; x < 4; ++x) qc[u][x] = qv[u][x];
        }
        #pragma unroll
        for (int u = 0; u < 4; ++u)
            *(float4*)&kf[(a4+u)*KFs + b4c] = make_float4(kv[u][0],kv[u][1],kv[u][2],kv[u][3]);
        #pragma unroll
        for (int u = 0; u < 4; ++u) {
            float s = ntabs[a4+u];
            st4(&sKd[(a4+u)*KDs + b4c], kv[u][0]*s, kv[u][1]*s, kv[u][2]*s, kv[u][3]*s);
        }
        {
            float w0 = ptabs[63-a4], w1 = ptabs[62-a4], w2 = ptabs[61-a4], w3 = ptabs[60-a4];
            #pragma unroll
            for (int e = 0; e < 4; ++e) {
                int row = b4c + e, col = a4 ^ SWZ(row);
                st4(&sKT[row*KTs + col], kv[0][e]*w0, kv[1][e]*w1, kv[2][e]*w2, kv[3][e]*w3);
                st4(&sB [row*BK  + col], vv[0][e], vv[1][e], vv[2][e], vv[3][e]);
            }
        }
        // prefetch chunk m+1 (stays in flight across raw barriers)
        if (m + 1 < Gn) {
            const size_t nrow = rowbase + Cn;
            #pragma unroll
            for (int u = 0; u < 4; ++u) {
                float4 tq = *(const float4*)&qin[(nrow + a4+u)*Dn + b4c];
                qv[u][0]=tq.x; qv[u][1]=tq.y; qv[u][2]=tq.z; qv[u][3]=tq.w;
                float4 tk = *(const float4*)&kin[(nrow + a4+u)*Dn + b4c];
                kv[u][0]=tk.x; kv[u][1]=tk.y; kv[u][2]=tk.z; kv[u][3]=tk.w;
                float4 tv = *(const float4*)&vin[(nrow + a4+u)*Dn + b4c];
                vv[u][0]=tv.x; vv[u][1]=tv.y; vv[u][2]=tv.z; vv[u][3]=tv.w;
            }
        }
        BAR();   // b1

        // ================= P1 =================
        if (wid < 2) {
            // kappa prefix scan, 16-batched
            const int d = tid;
            float kap = 0.f;
            for (int bb = 0; bb < 4; ++bb) {
                float rr[16];
                #pragma unroll
                for (int j = 0; j < 16; ++j) rr[j] = kf[(bb*16+j)*KFs + d];
                #pragma unroll
                for (int j = 0; j < 16; ++j) { kap = lam*kap + rr[j]; rr[j] = kap; }
                #pragma unroll
                for (int j = 0; j < 16; ++j) kf[(bb*16+j)*KFs + d] = rr[j];
            }
        } else if (wid < 4) {
            const int ic = (wid - 2)*32;
            #pragma unroll
            for (int jj = 0; jj < 2; ++jj) {
                const int jr = jj*32;
                f32x16 acc;
                #pragma unroll
                for (int r = 0; r < 16; ++r) acc[r] = 0.f;
                #pragma unroll
                for (int kk = 0; kk < 8; ++kk) {
                    short8v af = *(const short8v*)&sKd[(jr + l31)*KDs + kk*16 + lhi*8];
                    short8v bf = *(const short8v*)&sA [(ic + l31)*AK + 64 + kk*16 + lhi*8];
                    acc = __builtin_amdgcn_mfma_f32_32x32x16_bf16(af, bf, acc, 0, 0, 0);
                }
                const int i = ic + l31;
                #pragma unroll
                for (int q = 0; q < 4; ++q) {
                    int j0 = jr + 8*q + 4*lhi;
                    float v0 = (j0+0 <= i) ? acc[4*q+0] : 0.f;
                    float v1 = (j0+1 <= i) ? acc[4*q+1] : 0.f;
                    float v2 = (j0+2 <= i) ? acc[4*q+2] : 0.f;
                    float v3 = (j0+3 <= i) ? acc[4*q+3] : 0.f;
                    st4(&sA[i*AK + j0], v0, v1, v2, v3);
                }
            }
        } else {
            const int er0 = (wid-4)*32;
            #pragma unroll
            for (int ct = 0; ct < 4; ++ct)
                #pragma unroll
                for (int r = 0; r < 16; ++r) sacc[ct][r] *= lam64;
            #pragma unroll
            for (int kk = 0; kk < 4; ++kk) {
                int rA = er0 + l31;
                short8v af = *(const short8v*)&sKT[rA*KTs + ((kk*16 + lhi*8) ^ SWZ(rA))];
                #pragma unroll
                for (int ct = 0; ct < 4; ++ct) {
                    int rB = ct*32 + l31;
                    short8v bf = *(const short8v*)&sB[rB*BK + ((kk*16 + lhi*8) ^ SWZ(rB))];
                    sacc[ct] = __builtin_amdgcn_mfma_f32_32x32x16_bf16(af, bf, sacc[ct], 0, 0, 0);
                }
            }
        }
        // preload out-GEMM fragments stable in P1:
        //   paf: Q2 region of sA (written P0(m)); pbf: S^T region of sB (written P3(m-1)/init)
        short8v paf[8], pbf[8];
        #pragma unroll
        for (int kk = 0; kk < 8; ++kk) {
            paf[kk] = *(const short8v*)&sA[(r0 + l31)*AK + (kk+4)*16 + lhi*8];
            pbf[kk] = *(const short8v*)&sB[(c0 + l31)*BK + (kk+4)*16 + lhi*8];
        }
        BAR();   // b2

        // ================= P2 =================
        // LDS-fed frags: attn region of sA (written P1) + V^T swz (written P0)
        short8v afa[4], bfv[4];
        #pragma unroll
        for (int kk = 0; kk < 4; ++kk) {
            afa[kk] = *(const short8v*)&sA[(r0 + l31)*AK + kk*16 + lhi*8];
            int rB = c0 + l31;
            bfv[kk] = *(const short8v*)&sB[rB*BK + ((kk*16 + lhi*8) ^ SWZ(rB))];
        }
        // stepB operand reads (f32)
        float aI[4], aZ[4];
        {
            float4 zv = *(const float4*)&zf[b4c];
            #pragma unroll
            for (int u = 0; u < 4; ++u) {
                float4 kp = *(const float4*)&kf[(a4+u)*KFs + b4c];
                aI[u] = qc[u][0]*kp.x + qc[u][1]*kp.y + qc[u][2]*kp.z + qc[u][3]*kp.w;
                aZ[u] = qc[u][0]*zv.x + qc[u][1]*zv.y + qc[u][2]*zv.z + qc[u][3]*zv.w;
            }
        }
        // reg-only MFMAs fire immediately (operands preloaded in P1)
        f32x16 oacc;
        #pragma unroll
        for (int r = 0; r < 16; ++r) oacc[r] = 0.f;
        #pragma unroll
        for (int kk = 0; kk < 8; ++kk)
            oacc = __builtin_amdgcn_mfma_f32_32x32x16_bf16(paf[kk], pbf[kk], oacc, 0, 0, 0);
        // DPP reduce on the VALU pipe (overlaps MFMA)
        #pragma unroll
        for (int u = 0; u < 4; ++u) { aI[u] = red32(aI[u]); aZ[u] = red32(aZ[u]); }
        if ((lane & 31) == 16) {
            #pragma unroll
            for (int u = 0; u < 4; ++u) {
                izb[a4+u] = aI[u];
                czb[a4+u] = ptabs[a4+u+1]*aZ[u];
            }
        }
        // attn-half MFMAs (LDS-fed)
        #pragma unroll
        for (int kk = 0; kk < 4; ++kk)
            oacc = __builtin_amdgcn_mfma_f32_32x32x16_bf16(afa[kk], bfv[kk], oacc, 0, 0, 0);
        BAR();   // b3

        // ================= P3: epilogue + state/z update =================
        #pragma unroll
        for (int r = 0; r < 16; ++r) {
            int t = r0 + (r&3) + 8*(r>>2) + 4*lhi;
            float tz = fmaxf(fmaxf(izb[t], 1.f) + czb[t], 1.f);
            out[(rowbase + t)*Dn + c0 + l31] = oacc[r] * __builtin_amdgcn_rcpf(tz);
        }
        if (wid >= 4) {
            const int er0 = (wid-4)*32;
            #pragma unroll
            for (int ct = 0; ct < 4; ++ct) {
                const int d = ct*32 + l31;
                #pragma unroll
                for (int q = 0; q < 4; ++q) {
                    int e0 = er0 + 8*q + 4*lhi;
                    st4(&sB[d*BK + 64 + e0],
                        sacc[ct][4*q], sacc[ct][4*q+1], sacc[ct][4*q+2], sacc[ct][4*q+3]);
                }
            }
        }
        if (tid < 128) {
            zf[tid] = lam64*zf[tid] + kf[63*KFs + tid];   // kappa_63 = chunk k_sum
        }
        BAR();   // b4
    }
}

// -------------------------------------------------------------------------
extern "C" void kernel_launch(void* const* d_in, const int* in_sizes, int n_in,
                              void* d_out, int out_size, void* d_ws, size_t ws_size,
                              hipStream_t stream)
{
    const float* q  = (const float*)d_in[0];
    const float* k  = (const float*)d_in[1];
    const float* v  = (const float*)d_in[2];
    const float* ld = (const float*)d_in[3];
    float* out = (float*)d_out;

    float* A     = (float*)d_ws;
    float* ksumg = A     + (size_t)Bn*NGn*Dn*Dn;
    float* Sg    = ksumg + (size_t)Bn*NGn*Dn;
    float* zg    = Sg    + (size_t)Bn*NGn*Dn*Dn;

    float* outState = out      + (size_t)Bn*Tn*Dn;
    float* outZ     = outState + (size_t)Bn*Dn*Dn;

    hipLaunchKernelGGL(k1_mfma, dim3(NGn, Bn), dim3(512), 0, stream,
                       k, v, ld, A, ksumg);

    const int total2 = Bn*Dn*Dn + Bn*Dn;
    hipLaunchKernelGGL(k2_scan, dim3((total2 + 255)/256), dim3(256), 0, stream,
                       A, ksumg, ld, Sg, zg, outState, outZ);

    hipLaunchKernelGGL(k3_mfma, dim3(NGn, Bn), dim3(512), 0, stream,
                       q, k, v, ld, Sg, zg, out);
}

// Round 13
// 87.396 us; speedup vs baseline: 1.6472x; 1.6472x over previous
//
#include <hip/hip_runtime.h>
#include <math.h>

#define Bn  16
#define Tn  8192
#define Dn  128
#define Cn  64
#define Gn  8     // chunks per group
#define NGn 16    // groups per batch
#define GCn 512   // rows per group

typedef __attribute__((ext_vector_type(8)))  short short8v;
typedef __attribute__((ext_vector_type(16))) float f32x16;

#define AK  200   // A_cat stride (bf16), 64 rows: [attn(0..63) | Q2(64..191)]
#define BK  200   // B_cat stride (bf16), 128 rows: [d][ V^T(c, swz) | S^T(64+e) ]
#define KDs 136   // Kd stride (bf16), 64 rows  (lam^{-(j+1)} * k, row-major)
#define KTs 72    // KwT stride (bf16), 128 rows ([e][c] = lam^{63-c} * k[c][e], swz)
#define KFs 132   // kf stride (f32), 64 rows (k, then in-place prefix-decayed kappa)
#define K1s 72    // k1 kT/vT stride (bf16)

#define SWZ(row) ((((row) >> 2) & 7) << 3)

// raw barrier: LDS visibility only, does NOT drain vmcnt (keeps prefetch in flight)
#define BAR() do { asm volatile("s_waitcnt lgkmcnt(0)" ::: "memory"); \
                   __builtin_amdgcn_s_barrier(); \
                   asm volatile("" ::: "memory"); } while (0)

__device__ __forceinline__ float sig_(float x){ return 1.0f/(1.0f+expf(-x)); }

__device__ __forceinline__ unsigned short f2bf(float f){
    __bf16 h = (__bf16)f;
    return __builtin_bit_cast(unsigned short, h);
}
__device__ __forceinline__ void st4(unsigned short* p, float a, float b, float c, float d){
    ushort4 u; u.x = f2bf(a); u.y = f2bf(b); u.z = f2bf(c); u.w = f2bf(d);
    *(ushort4*)p = u;   // ds_write_b64
}

// VALU-pipe cross-lane add (DPP); CTRL is an immediate via template param
template<int CTRL>
__device__ __forceinline__ float dppadd(float x){
    int y = __builtin_amdgcn_update_dpp(0, __builtin_bit_cast(int, x), CTRL, 0xf, 0xf, true);
    return x + __builtin_bit_cast(float, y);
}
// reduce over each 32-lane half: quad xor1, xor2, row ror4, ror8, bcast15
// result valid in lanes 16..31 (sum of lanes 0..31) and 48..63 (sum of 32..63)
__device__ __forceinline__ float red32(float x){
    x = dppadd<0xB1>(x);    // quad_perm [1,0,3,2]
    x = dppadd<0x4E>(x);    // quad_perm [2,3,0,1]
    x = dppadd<0x124>(x);   // row_ror:4
    x = dppadd<0x128>(x);   // row_ror:8
    x = dppadd<0x142>(x);   // row_bcast:15
    return x;
}

// -------------------------------------------------------------------------
// K1 (MFMA): A_g = (Kw)^T @ V ; ksum_g f32 register partials.  (HBM-floor)
// -------------------------------------------------------------------------
__global__ __launch_bounds__(512)
void k1_mfma(const float* __restrict__ kin, const float* __restrict__ vin,
             const float* __restrict__ log_decay,
             float* __restrict__ A, float* __restrict__ ksumg)
{
    const int g = blockIdx.x, b = blockIdx.y;
    const int tid  = threadIdx.x;
    const int wid  = tid >> 6;
    const int lane = tid & 63;
    const int l31  = lane & 31;
    const int lhi  = lane >> 5;
    const float lam = sig_(log_decay[0]);

    __shared__ __align__(16) unsigned short kT[128*K1s];
    __shared__ __align__(16) unsigned short vT[128*K1s];
    __shared__ float wt[GCn];
    __shared__ __align__(16) float ps[16*132];

    wt[tid] = powf(lam, (float)(GCn-1 - tid));

    const size_t base = ((size_t)b*Tn + (size_t)g*GCn)*Dn;
    const int rb = tid >> 5;
    const int cb = (tid & 31)*4;

    f32x16 acc[2];
    #pragma unroll
    for (int p = 0; p < 2; ++p)
        #pragma unroll
        for (int r = 0; r < 16; ++r) acc[p][r] = 0.f;
    float ksp[4] = {0.f, 0.f, 0.f, 0.f};

    float kv[4][4], vv[4][4];
    {
        const float* kp = kin + base;
        const float* vp = vin + base;
        #pragma unroll
        for (int u = 0; u < 4; ++u) {
            float4 t4 = *(const float4*)&kp[(size_t)(rb*4+u)*Dn + cb];
            kv[u][0]=t4.x; kv[u][1]=t4.y; kv[u][2]=t4.z; kv[u][3]=t4.w;
            float4 s4 = *(const float4*)&vp[(size_t)(rb*4+u)*Dn + cb];
            vv[u][0]=s4.x; vv[u][1]=s4.y; vv[u][2]=s4.z; vv[u][3]=s4.w;
        }
    }
    BAR();

    const int tr0 = (wid >> 2)*2;
    const int tc  = (wid & 3)*32;

    for (int t = 0; t < 8; ++t) {
        const int r0 = rb*4;
        float w0 = wt[t*64 + r0+0], w1 = wt[t*64 + r0+1];
        float w2 = wt[t*64 + r0+2], w3 = wt[t*64 + r0+3];
        #pragma unroll
        for (int e = 0; e < 4; ++e) {
            int row = cb+e, col = r0 ^ SWZ(row);
            float a0 = kv[0][e]*w0, a1 = kv[1][e]*w1, a2 = kv[2][e]*w2, a3 = kv[3][e]*w3;
            ksp[e] += (a0 + a1) + (a2 + a3);
            st4(&kT[row*K1s + col], a0, a1, a2, a3);
            st4(&vT[row*K1s + col], vv[0][e], vv[1][e], vv[2][e], vv[3][e]);
        }
        BAR();

        if (t < 7) {
            const float* kp = kin + base + (size_t)(t+1)*64*Dn;
            const float* vp = vin + base + (size_t)(t+1)*64*Dn;
            #pragma unroll
            for (int u = 0; u < 4; ++u) {
                float4 t4 = *(const float4*)&kp[(size_t)(rb*4+u)*Dn + cb];
                kv[u][0]=t4.x; kv[u][1]=t4.y; kv[u][2]=t4.z; kv[u][3]=t4.w;
                float4 s4 = *(const float4*)&vp[(size_t)(rb*4+u)*Dn + cb];
                vv[u][0]=s4.x; vv[u][1]=s4.y; vv[u][2]=s4.z; vv[u][3]=s4.w;
            }
        }

        #pragma unroll
        for (int kk = 0; kk < 4; ++kk) {
            int rB = tc + l31;
            short8v bf = *(const short8v*)&vT[rB*K1s + ((kk*16 + lhi*8) ^ SWZ(rB))];
            #pragma unroll
            for (int p = 0; p < 2; ++p) {
                int rA = (tr0+p)*32 + l31;
                short8v af = *(const short8v*)&kT[rA*K1s + ((kk*16 + lhi*8) ^ SWZ(rA))];
                acc[p] = __builtin_amdgcn_mfma_f32_32x32x16_bf16(af, bf, acc[p], 0, 0, 0);
            }
        }
        BAR();
    }

    float* Ab = A + ((size_t)(b*NGn + g))*Dn*Dn;
    #pragma unroll
    for (int p = 0; p < 2; ++p) {
        #pragma unroll
        for (int r = 0; r < 16; ++r) {
            int i = (tr0+p)*32 + (r&3) + 8*(r>>2) + 4*lhi;
            Ab[(size_t)i*Dn + tc + l31] = acc[p][r];
        }
    }

    *(float4*)&ps[rb*132 + cb] = make_float4(ksp[0], ksp[1], ksp[2], ksp[3]);
    BAR();
    if (tid < Dn) {
        float s = 0.f;
        #pragma unroll
        for (int q = 0; q < 16; ++q) s += ps[q*132 + tid];
        ksumg[((size_t)(b*NGn+g))*Dn + tid] = s;
    }
}

// -------------------------------------------------------------------------
// K2: exclusive scan over groups; final carry -> d_out state/z sections.
// -------------------------------------------------------------------------
__global__ __launch_bounds__(256)
void k2_scan(const float* __restrict__ A, const float* __restrict__ ksumg,
             const float* __restrict__ log_decay,
             float* __restrict__ Sg, float* __restrict__ zg,
             float* __restrict__ outState, float* __restrict__ outZ)
{
    const int idx = blockIdx.x*256 + threadIdx.x;
    const float lam = sig_(log_decay[0]);
    const float dG = powf(lam, (float)GCn);
    const int NSTATE = Bn*Dn*Dn;
    if (idx < NSTATE) {
        const int b = idx >> 14, ij = idx & 16383;
        float s = 0.f;
        #pragma unroll
        for (int g = 0; g < NGn; ++g) {
            size_t o = (((size_t)(b*NGn+g)) << 14) + ij;
            Sg[o] = s;
            s = dG*s + A[o];
        }
        outState[idx] = s;
    } else if (idx < NSTATE + Bn*Dn) {
        const int j = idx - NSTATE, b = j >> 7, d = j & 127;
        float s = 0.f;
        #pragma unroll
        for (int g = 0; g < NGn; ++g) {
            size_t o = (size_t)(b*NGn+g)*Dn + d;
            zg[o] = s;
            s = dG*s + ksumg[o];
        }
        outZ[j] = s;
    }
}

// -------------------------------------------------------------------------
// K3: round-9 schedule (verified 65.5us) with stepB reduction moved from
//     __shfl_xor (LDS pipe, serial chain) to DPP v_add_f32 (VALU pipe).
//  P0: stage(m) from regs; prefetch(m+1); b1
//  P1: w0-1 kappa(batched) | w2-3 attn | w4-7 state MFMA; b2
//  P2: stepB (qc regs + kf + zf, DPP reduce) + out-GEMM (12 kk, LDS-fed); b3
//  P3: epilogue stores; S^T writeback; z update; b4
// -------------------------------------------------------------------------
__global__ __launch_bounds__(512, 2)
void k3_mfma(const float* __restrict__ qin, const float* __restrict__ kin,
             const float* __restrict__ vin, const float* __restrict__ log_decay,
             const float* __restrict__ Sg, const float* __restrict__ zg,
             float* __restrict__ out)
{
    const int g = blockIdx.x, b = blockIdx.y;
    const int tid  = threadIdx.x;
    const int wid  = tid >> 6;
    const int lane = tid & 63;
    const int l31  = lane & 31;
    const int lhi  = lane >> 5;
    const float lam   = sig_(log_decay[0]);
    const float lam64 = powf(lam, 64.0f);

    __shared__ __align__(16) unsigned short sA [64*AK];
    __shared__ __align__(16) unsigned short sB [128*BK];
    __shared__ __align__(16) unsigned short sKd[64*KDs];
    __shared__ __align__(16) unsigned short sKT[128*KTs];
    __shared__ __align__(16) float kf[64*KFs];
    __shared__ __align__(16) float zf[128];
    __shared__ __align__(16) float izb[64], czb[64];
    __shared__ float ptabs[66], ntabs[64];

    const int bg = b*NGn + g;
    const size_t base = (size_t)b*Tn + (size_t)g*Gn*Cn;

    // ---- init ----
    if (tid < 66)  ptabs[tid] = powf(lam, (float)tid);
    if (tid >= 66 && tid < 130) ntabs[tid-66] = powf(lam, -(float)(tid-65));
    if (tid < 128) zf[tid] = zg[(size_t)bg*Dn + tid];

    f32x16 sacc[4];
    if (wid >= 4) {
        const float* Sgp = Sg + ((size_t)bg << 14);
        const int er0 = (wid-4)*32;
        #pragma unroll
        for (int ct = 0; ct < 4; ++ct) {
            const int d = ct*32 + l31;
            #pragma unroll
            for (int r = 0; r < 16; ++r) {
                int e = er0 + (r&3) + 8*(r>>2) + 4*lhi;
                sacc[ct][r] = Sgp[e*Dn + d];
            }
            #pragma unroll
            for (int q = 0; q < 4; ++q) {
                int e0 = er0 + 8*q + 4*lhi;
                st4(&sB[d*BK + 64 + e0],
                    sacc[ct][4*q], sacc[ct][4*q+1], sacc[ct][4*q+2], sacc[ct][4*q+3]);
            }
        }
    }

    // unified staging map: rows a4..a4+3, cols b4c..b4c+3 (q, k, v)
    const int a4  = (tid >> 5)*4;
    const int b4c = (tid & 31)*4;

    // ---- prologue: prefetch chunk 0 ----
    float qv[4][4], kv[4][4], vv[4][4];
    #pragma unroll
    for (int u = 0; u < 4; ++u) {
        float4 tq = *(const float4*)&qin[(base + a4+u)*Dn + b4c];
        qv[u][0]=tq.x; qv[u][1]=tq.y; qv[u][2]=tq.z; qv[u][3]=tq.w;
        float4 tk = *(const float4*)&kin[(base + a4+u)*Dn + b4c];
        kv[u][0]=tk.x; kv[u][1]=tk.y; kv[u][2]=tk.z; kv[u][3]=tk.w;
        float4 tv = *(const float4*)&vin[(base + a4+u)*Dn + b4c];
        vv[u][0]=tv.x; vv[u][1]=tv.y; vv[u][2]=tv.z; vv[u][3]=tv.w;
    }

    const int r0 = (wid >> 2)*32;
    const int c0 = (wid & 3)*32;

    BAR();   // init visible

    for (int m = 0; m < Gn; ++m) {
        const size_t rowbase = base + (size_t)m*Cn;

        // ================= P0: stage chunk m from regs =================
        float qc[4][4];   // q kept live to P2 (stepB)
        #pragma unroll
        for (int u = 0; u < 4; ++u) {
            const int row = a4 + u;
            const float s = ptabs[row+1];
            st4(&sA[row*AK + 64 + b4c], qv[u][0]*s, qv[u][1]*s, qv[u][2]*s, qv[u][3]*s);
            #pragma unroll
            for (int x = 0; x < 4; ++x) qc[u][x] = qv[u][x];
        }
        #pragma unroll
        for (int u = 0; u < 4; ++u)
            *(float4*)&kf[(a4+u)*KFs + b4c] = make_float4(kv[u][0],kv[u][1],kv[u][2],kv[u][3]);
        #pragma unroll
        for (int u = 0; u < 4; ++u) {
            float s = ntabs[a4+u];
            st4(&sKd[(a4+u)*KDs + b4c], kv[u][0]*s, kv[u][1]*s, kv[u][2]*s, kv[u][3]*s);
        }
        {
            float w0 = ptabs[63-a4], w1 = ptabs[62-a4], w2 = ptabs[61-a4], w3 = ptabs[60-a4];
            #pragma unroll
            for (int e = 0; e < 4; ++e) {
                int row = b4c + e, col = a4 ^ SWZ(row);
                st4(&sKT[row*KTs + col], kv[0][e]*w0, kv[1][e]*w1, kv[2][e]*w2, kv[3][e]*w3);
                st4(&sB [row*BK  + col], vv[0][e], vv[1][e], vv[2][e], vv[3][e]);
            }
        }
        // prefetch chunk m+1 (stays in flight across raw barriers)
        if (m + 1 < Gn) {
            const size_t nrow = rowbase + Cn;
            #pragma unroll
            for (int u = 0; u < 4; ++u) {
                float4 tq = *(const float4*)&qin[(nrow + a4+u)*Dn + b4c];
                qv[u][0]=tq.x; qv[u][1]=tq.y; qv[u][2]=tq.z; qv[u][3]=tq.w;
                float4 tk = *(const float4*)&kin[(nrow + a4+u)*Dn + b4c];
                kv[u][0]=tk.x; kv[u][1]=tk.y; kv[u][2]=tk.z; kv[u][3]=tk.w;
                float4 tv = *(const float4*)&vin[(nrow + a4+u)*Dn + b4c];
                vv[u][0]=tv.x; vv[u][1]=tv.y; vv[u][2]=tv.z; vv[u][3]=tv.w;
            }
        }
        BAR();   // b1

        // ================= P1 =================
        if (wid < 2) {
            // kappa prefix scan, 16-batched
            const int d = tid;
            float kap = 0.f;
            for (int bb = 0; bb < 4; ++bb) {
                float rr[16];
                #pragma unroll
                for (int j = 0; j < 16; ++j) rr[j] = kf[(bb*16+j)*KFs + d];
                #pragma unroll
                for (int j = 0; j < 16; ++j) { kap = lam*kap + rr[j]; rr[j] = kap; }
                #pragma unroll
                for (int j = 0; j < 16; ++j) kf[(bb*16+j)*KFs + d] = rr[j];
            }
        } else if (wid < 4) {
            const int ic = (wid - 2)*32;
            #pragma unroll
            for (int jj = 0; jj < 2; ++jj) {
                const int jr = jj*32;
                f32x16 acc;
                #pragma unroll
                for (int r = 0; r < 16; ++r) acc[r] = 0.f;
                #pragma unroll
                for (int kk = 0; kk < 8; ++kk) {
                    short8v af = *(const short8v*)&sKd[(jr + l31)*KDs + kk*16 + lhi*8];
                    short8v bf = *(const short8v*)&sA [(ic + l31)*AK + 64 + kk*16 + lhi*8];
                    acc = __builtin_amdgcn_mfma_f32_32x32x16_bf16(af, bf, acc, 0, 0, 0);
                }
                const int i = ic + l31;
                #pragma unroll
                for (int q = 0; q < 4; ++q) {
                    int j0 = jr + 8*q + 4*lhi;
                    float v0 = (j0+0 <= i) ? acc[4*q+0] : 0.f;
                    float v1 = (j0+1 <= i) ? acc[4*q+1] : 0.f;
                    float v2 = (j0+2 <= i) ? acc[4*q+2] : 0.f;
                    float v3 = (j0+3 <= i) ? acc[4*q+3] : 0.f;
                    st4(&sA[i*AK + j0], v0, v1, v2, v3);
                }
            }
        } else {
            const int er0 = (wid-4)*32;
            #pragma unroll
            for (int ct = 0; ct < 4; ++ct)
                #pragma unroll
                for (int r = 0; r < 16; ++r) sacc[ct][r] *= lam64;
            #pragma unroll
            for (int kk = 0; kk < 4; ++kk) {
                int rA = er0 + l31;
                short8v af = *(const short8v*)&sKT[rA*KTs + ((kk*16 + lhi*8) ^ SWZ(rA))];
                #pragma unroll
                for (int ct = 0; ct < 4; ++ct) {
                    int rB = ct*32 + l31;
                    short8v bf = *(const short8v*)&sB[rB*BK + ((kk*16 + lhi*8) ^ SWZ(rB))];
                    sacc[ct] = __builtin_amdgcn_mfma_f32_32x32x16_bf16(af, bf, sacc[ct], 0, 0, 0);
                }
            }
        }
        BAR();   // b2

        // ================= P2 =================
        // stepB: f32 denominator from registers; DPP reduce on the VALU pipe
        {
            float aI[4], aZ[4];
            float4 zv = *(const float4*)&zf[b4c];
            #pragma unroll
            for (int u = 0; u < 4; ++u) {
                float4 kp = *(const float4*)&kf[(a4+u)*KFs + b4c];
                aI[u] = qc[u][0]*kp.x + qc[u][1]*kp.y + qc[u][2]*kp.z + qc[u][3]*kp.w;
                aZ[u] = qc[u][0]*zv.x + qc[u][1]*zv.y + qc[u][2]*zv.z + qc[u][3]*zv.w;
            }
            #pragma unroll
            for (int u = 0; u < 4; ++u) { aI[u] = red32(aI[u]); aZ[u] = red32(aZ[u]); }
            if ((lane & 31) == 16) {
                #pragma unroll
                for (int u = 0; u < 4; ++u) {
                    izb[a4+u] = aI[u];
                    czb[a4+u] = ptabs[a4+u+1]*aZ[u];
                }
            }
        }
        // out GEMM: D[i][d] = sum_k A_cat[i][k] * Bcat^T[d][k]
        f32x16 oacc;
        #pragma unroll
        for (int r = 0; r < 16; ++r) oacc[r] = 0.f;
        #pragma unroll
        for (int kk = 0; kk < 12; ++kk) {
            short8v af = *(const short8v*)&sA[(r0 + l31)*AK + kk*16 + lhi*8];
            int rB = c0 + l31;
            int coff = kk*16 + lhi*8;
            if (kk < 4) coff ^= SWZ(rB);          // V^T region is swizzled
            short8v bf = *(const short8v*)&sB[rB*BK + coff];
            oacc = __builtin_amdgcn_mfma_f32_32x32x16_bf16(af, bf, oacc, 0, 0, 0);
        }
        BAR();   // b3

        // ================= P3: epilogue + state/z update =================
        #pragma unroll
        for (int r = 0; r < 16; ++r) {
            int t = r0 + (r&3) + 8*(r>>2) + 4*lhi;
            float tz = fmaxf(fmaxf(izb[t], 1.f) + czb[t], 1.f);
            out[(rowbase + t)*Dn + c0 + l31] = oacc[r] * __builtin_amdgcn_rcpf(tz);
        }
        if (wid >= 4) {
            const int er0 = (wid-4)*32;
            #pragma unroll
            for (int ct = 0; ct < 4; ++ct) {
                const int d = ct*32 + l31;
                #pragma unroll
                for (int q = 0; q < 4; ++q) {
                    int e0 = er0 + 8*q + 4*lhi;
                    st4(&sB[d*BK + 64 + e0],
                        sacc[ct][4*q], sacc[ct][4*q+1], sacc[ct][4*q+2], sacc[ct][4*q+3]);
                }
            }
        }
        if (tid < 128) {
            zf[tid] = lam64*zf[tid] + kf[63*KFs + tid];   // kappa_63 = chunk k_sum
        }
        BAR();   // b4
    }
}

// -------------------------------------------------------------------------
extern "C" void kernel_launch(void* const* d_in, const int* in_sizes, int n_in,
                              void* d_out, int out_size, void* d_ws, size_t ws_size,
                              hipStream_t stream)
{
    const float* q  = (const float*)d_in[0];
    const float* k  = (const float*)d_in[1];
    const float* v  = (const float*)d_in[2];
    const float* ld = (const float*)d_in[3];
    float* out = (float*)d_out;

    float* A     = (float*)d_ws;
    float* ksumg = A     + (size_t)Bn*NGn*Dn*Dn;
    float* Sg    = ksumg + (size_t)Bn*NGn*Dn;
    float* zg    = Sg    + (size_t)Bn*NGn*Dn*Dn;

    float* outState = out      + (size_t)Bn*Tn*Dn;
    float* outZ     = outState + (size_t)Bn*Dn*Dn;

    hipLaunchKernelGGL(k1_mfma, dim3(NGn, Bn), dim3(512), 0, stream,
                       k, v, ld, A, ksumg);

    const int total2 = Bn*Dn*Dn + Bn*Dn;
    hipLaunchKernelGGL(k2_scan, dim3((total2 + 255)/256), dim3(256), 0, stream,
                       A, ksumg, ld, Sg, zg, outState, outZ);

    hipLaunchKernelGGL(k3_mfma, dim3(NGn, Bn), dim3(512), 0, stream,
                       q, k, v, ld, Sg, zg, out);
}